// Round 4
// baseline (397.447 us; speedup 1.0000x reference)
//
#include <hip/hip_runtime.h>
#include <stdint.h>

// (B,P,C,H,W)=(256,10,32,8,8); Tm=19, Ta=10, hw=64. All I/O fp32.
// Horner: A_0=[F_0;1]; A_{p+1}=A_p*M_p+[F_{p+1};1] (p=0..8) -> A_9=[G;W]
// out[b,t,c,j] = (G[c,:].M_t[:,j]) / (W.M_t[:,j] + eps)
//
// R3 was LDS-pipe-bound (~180k DS cyc/CU = 77us): broadcast row reads gave
// 1x register reuse. This version: 2D register tiling, A stored transposed
// (At[k][r], stride 40, 1-bit swizzle), phase-2 = 4 barrier-free waves
// streaming M in 4KB k-chunks. ~2 B per FMA delivered from LDS.

#define EPSV 1e-6f

// element A[r][k] lives at k*40 + (r ^ swz(k)), swz(k) = ((k>>2)&1)<<2.
// max offset k*40 + 39 (rows 0..35). Quads stay contiguous & 16B-aligned
// because r0 and swz are both multiples of 4.
__device__ __forceinline__ int at_off(int k, int r4) {
    return k * 40 + (r4 ^ (((k >> 2) & 1) << 2));
}

__global__ __launch_bounds__(512) void k_fused(
    const float* __restrict__ feats,   // (256,10,32,64)
    const float* __restrict__ sim,     // (256,19,64,64)
    float* __restrict__ out)           // (2560,32,64)
{
    __shared__ __attribute__((aligned(16))) float Mbuf[8192];  // phase1 M dbuf; phase2 per-wave chunks
    __shared__ __attribute__((aligned(16))) float At[5120];    // 2 x 64*40 transposed A
    __shared__ __attribute__((aligned(16))) float Wrow[64];
    __shared__ __attribute__((aligned(16))) float wvec[256];

    const int tid  = threadIdx.x;
    const int lane = tid & 63;
    const int wave = tid >> 6;
    const int b    = blockIdx.x;

    const float* fb = feats + (size_t)b * 20480;   // 10*32*64
    const float* sb = sim   + (size_t)b * 77824;   // 19*64*64

    // ---- init At[0] = [F_0 ; ones ; zero-pad]^T : thread (k=lane, rows wave*4..+3)
    {
        const int k = lane;
        float4 v;
        v.x = fb[(wave * 4 + 0) * 64 + k];
        v.y = fb[(wave * 4 + 1) * 64 + k];
        v.z = fb[(wave * 4 + 2) * 64 + k];
        v.w = fb[(wave * 4 + 3) * 64 + k];
        *(float4*)&At[at_off(k, wave * 4)] = v;
        if (wave == 0) {                       // rows 32..35 = [1,0,0,0]
            float4 e; e.x = 1.f; e.y = 0.f; e.z = 0.f; e.w = 0.f;
            *(float4*)&At[at_off(k, 32)] = e;
        }
    }
    // ---- stage M_0 into Mbuf[0] ----
    #pragma unroll
    for (int q = 0; q < 2; ++q) {
        float4 v = *(const float4*)&sb[q * 2048 + tid * 4];
        *(float4*)&Mbuf[q * 2048 + tid * 4] = v;
    }
    __syncthreads();

    // phase-1 tile coords: 144 workers, 4x4 tiles over 36(rows)x64(cols)
    const bool act1 = tid < 144;
    const int r0 = (tid >> 4) * 4;      // 0,4,...,32
    const int j0 = (tid & 15) * 4;

    float4 creg[4];                     // phase-2 first-chunk prefetch

    for (int p = 0; p < 9; ++p) {
        const int mcur = (p & 1) * 4096;
        const int acur = (p & 1) * 2560;
        const int anxt = ((p + 1) & 1) * 2560;

        float4 mst[2];
        if (p < 8) {                    // global->reg prefetch of M_{p+1}
            #pragma unroll
            for (int q = 0; q < 2; ++q)
                mst[q] = *(const float4*)&sb[(p + 1) * 4096 + q * 2048 + tid * 4];
        }
        if (p == 8 && wave < 4) {       // prefetch phase-2 chunk 0 (t = wave)
            const float* src = sb + (9 + wave) * 4096;
            #pragma unroll
            for (int q = 0; q < 4; ++q)
                creg[q] = *(const float4*)&src[q * 256 + lane * 4];
        }

        float f[4][4];                  // F_{p+1} tile (row-32 tile: [1;0;0;0])
        if (act1) {
            if (r0 < 32) {
                #pragma unroll
                for (int i = 0; i < 4; ++i) {
                    float4 v = *(const float4*)&fb[(p + 1) * 2048 + (r0 + i) * 64 + j0];
                    f[i][0] = v.x; f[i][1] = v.y; f[i][2] = v.z; f[i][3] = v.w;
                }
            } else {
                #pragma unroll
                for (int i = 0; i < 4; ++i)
                    #pragma unroll
                    for (int c = 0; c < 4; ++c) f[i][c] = (i == 0) ? 1.f : 0.f;
            }
        }

        if (act1) {
            float acc[16];
            #pragma unroll
            for (int i = 0; i < 16; ++i) acc[i] = 0.f;
            #pragma unroll
            for (int k = 0; k < 64; ++k) {
                const float4 a = *(const float4*)&At[acur + at_off(k, r0)];   // A[r0:+4][k]
                const float4 m = *(const float4*)&Mbuf[mcur + k * 64 + j0];   // M[k][j0:+4]
                acc[0]  += a.x*m.x; acc[1]  += a.x*m.y; acc[2]  += a.x*m.z; acc[3]  += a.x*m.w;
                acc[4]  += a.y*m.x; acc[5]  += a.y*m.y; acc[6]  += a.y*m.z; acc[7]  += a.y*m.w;
                acc[8]  += a.z*m.x; acc[9]  += a.z*m.y; acc[10] += a.z*m.z; acc[11] += a.z*m.w;
                acc[12] += a.w*m.x; acc[13] += a.w*m.y; acc[14] += a.w*m.z; acc[15] += a.w*m.w;
            }
            // epilogue: A' = acc + F', written transposed into At[anxt]
            #pragma unroll
            for (int c = 0; c < 4; ++c) {
                float4 w4;
                w4.x = acc[0*4 + c] + f[0][c];
                w4.y = acc[1*4 + c] + f[1][c];
                w4.z = acc[2*4 + c] + f[2][c];
                w4.w = acc[3*4 + c] + f[3][c];
                *(float4*)&At[anxt + at_off(j0 + c, r0)] = w4;
            }
            if (p == 8 && r0 == 32) {   // contiguous copy of weight row W = A9[32][:]
                float4 w;
                w.x = acc[0] + 1.f; w.y = acc[1] + 1.f;
                w.z = acc[2] + 1.f; w.w = acc[3] + 1.f;
                *(float4*)&Wrow[j0] = w;
            }
        }
        if (p < 8) {                    // spill M_{p+1} into the other buffer
            const int nb = ((p + 1) & 1) * 4096;
            #pragma unroll
            for (int q = 0; q < 2; ++q)
                *(float4*)&Mbuf[nb + q * 2048 + tid * 4] = mst[q];
        }
        __syncthreads();
    }
    // At[2560..] holds [G;W]^T. Phase 2: waves 0-3, fully independent (no barriers).
    if (wave >= 4) return;

    const int r0b = (lane >> 4) * 8;    // 0,8,16,24
    const int j0b = (lane & 15) * 4;
    float* mch = &Mbuf[wave * 1024];    // this wave's 4KB k-chunk buffer
    const int nt = (wave < 2) ? 3 : 2;  // waves 0,1: t={w,w+4,w+8}; 2,3: t={w,w+4}

    for (int rd = 0; rd < nt; ++rd) {
        const int t = wave + rd * 4;
        float acc[32];
        #pragma unroll
        for (int i = 0; i < 32; ++i) acc[i] = 0.f;
        float wv = 0.f;

        #pragma unroll
        for (int c = 0; c < 4; ++c) {
            // spill prefetched chunk c (in-order DS => prior reads already done)
            #pragma unroll
            for (int q = 0; q < 4; ++q)
                *(float4*)&mch[q * 256 + lane * 4] = creg[q];
            // prefetch next chunk (same t, or chunk 0 of next t)
            const float* nsrc = nullptr;
            if (c < 3)            nsrc = sb + (9 + t) * 4096 + (c + 1) * 1024;
            else if (rd + 1 < nt) nsrc = sb + (9 + t + 4) * 4096;
            if (nsrc) {
                #pragma unroll
                for (int q = 0; q < 4; ++q)
                    creg[q] = *(const float4*)&nsrc[q * 256 + lane * 4];
            }
            float wk[16];
            #pragma unroll
            for (int q = 0; q < 4; ++q) {
                float4 wq = *(const float4*)&Wrow[c * 16 + q * 4];   // broadcast
                wk[q*4+0] = wq.x; wk[q*4+1] = wq.y; wk[q*4+2] = wq.z; wk[q*4+3] = wq.w;
            }
            #pragma unroll
            for (int kk = 0; kk < 16; ++kk) {
                const int k = c * 16 + kk;
                const float4 a0 = *(const float4*)&At[2560 + at_off(k, r0b)];
                const float4 a1 = *(const float4*)&At[2560 + at_off(k, r0b + 4)];
                const float4 m  = *(const float4*)&mch[kk * 64 + j0b];
                wv += wk[kk] * mch[kk * 64 + lane];
                acc[0]  += a0.x*m.x; acc[1]  += a0.x*m.y; acc[2]  += a0.x*m.z; acc[3]  += a0.x*m.w;
                acc[4]  += a0.y*m.x; acc[5]  += a0.y*m.y; acc[6]  += a0.y*m.z; acc[7]  += a0.y*m.w;
                acc[8]  += a0.z*m.x; acc[9]  += a0.z*m.y; acc[10] += a0.z*m.z; acc[11] += a0.z*m.w;
                acc[12] += a0.w*m.x; acc[13] += a0.w*m.y; acc[14] += a0.w*m.z; acc[15] += a0.w*m.w;
                acc[16] += a1.x*m.x; acc[17] += a1.x*m.y; acc[18] += a1.x*m.z; acc[19] += a1.x*m.w;
                acc[20] += a1.y*m.x; acc[21] += a1.y*m.y; acc[22] += a1.y*m.z; acc[23] += a1.y*m.w;
                acc[24] += a1.z*m.x; acc[25] += a1.z*m.y; acc[26] += a1.z*m.z; acc[27] += a1.z*m.w;
                acc[28] += a1.w*m.x; acc[29] += a1.w*m.y; acc[30] += a1.w*m.z; acc[31] += a1.w*m.w;
            }
        }
        // redistribute denominator within the wave (in-order DS, no barrier)
        wvec[wave * 64 + lane] = wv;
        float4 wv4 = *(const float4*)&wvec[wave * 64 + j0b];
        float4 rw;
        rw.x = 1.f / (wv4.x + EPSV);
        rw.y = 1.f / (wv4.y + EPSV);
        rw.z = 1.f / (wv4.z + EPSV);
        rw.w = 1.f / (wv4.w + EPSV);

        float* ob = out + ((size_t)b * 10 + t) * 2048;
        #pragma unroll
        for (int i = 0; i < 8; ++i) {
            const int base = (i < 4) ? (i * 4) : (16 + (i - 4) * 4);
            float4 o;
            o.x = acc[base + 0] * rw.x;
            o.y = acc[base + 1] * rw.y;
            o.z = acc[base + 2] * rw.z;
            o.w = acc[base + 3] * rw.w;
            *(float4*)&ob[(r0b + i) * 64 + j0b] = o;
        }
    }
}

extern "C" void kernel_launch(void* const* d_in, const int* in_sizes, int n_in,
                              void* d_out, int out_size, void* d_ws, size_t ws_size,
                              hipStream_t stream) {
    const float* feats = (const float*)d_in[0];
    const float* sim   = (const float*)d_in[1];
    k_fused<<<256, 512, 0, stream>>>(feats, sim, (float*)d_out);
}

// Round 5
// 169.699 us; speedup vs baseline: 2.3421x; 2.3421x over previous
//
#include <hip/hip_runtime.h>
#include <stdint.h>

// (B,P,C,H,W)=(256,10,32,8,8); Tm=19, Ta=10, hw=64. All I/O fp32.
// Horner: A_0=[F_0;1]; A_{p+1}=A_p*M_p+[F_{p+1};1] (p=0..8) -> A_9=[G;W]
// out[b,t,c,j] = (G[c,:].M_t[:,j]) / (W.M_t[:,j] + eps)
//
// R4 post-mortem: correct but spilled to scratch (WRITE 410MB, VALUBusy 5%).
// Fixes: __launch_bounds__(512,1) -> 256 VGPR cap; drop wk[] array; roll the
// phase-2 chunk loop; partial-unroll phase-1 k-loop; phase 2 on all 8 waves.

#define EPSV 1e-6f

// element A[r][k] lives at k*40 + (r ^ swz(k)), swz(k) = ((k>>2)&1)<<2.
// quads stay contiguous & 16B-aligned (r0, swz both multiples of 4).
__device__ __forceinline__ int at_off(int k, int r4) {
    return k * 40 + (r4 ^ (((k >> 2) & 1) << 2));
}

__global__ __launch_bounds__(512, 1) void k_fused(
    const float* __restrict__ feats,   // (256,10,32,64)
    const float* __restrict__ sim,     // (256,19,64,64)
    float* __restrict__ out)           // (2560,32,64)
{
    __shared__ __attribute__((aligned(16))) float Mbuf[8192];  // ph1 M dbuf / ph2 8x1024 chunks
    __shared__ __attribute__((aligned(16))) float At[5120];    // 2 x 64*40 transposed A
    __shared__ __attribute__((aligned(16))) float Wrow[64];
    __shared__ __attribute__((aligned(16))) float wvec[512];

    const int tid  = threadIdx.x;
    const int lane = tid & 63;
    const int wave = tid >> 6;
    const int b    = blockIdx.x;

    const float* fb = feats + (size_t)b * 20480;   // 10*32*64
    const float* sb = sim   + (size_t)b * 77824;   // 19*64*64

    // ---- init At[0] = [F_0 ; e0 ; pad]^T : thread (k=lane, rows wave*4..+3)
    {
        const int k = lane;
        float4 v;
        v.x = fb[(wave * 4 + 0) * 64 + k];
        v.y = fb[(wave * 4 + 1) * 64 + k];
        v.z = fb[(wave * 4 + 2) * 64 + k];
        v.w = fb[(wave * 4 + 3) * 64 + k];
        *(float4*)&At[at_off(k, wave * 4)] = v;
        if (wave == 0) {                       // rows 32..35 = [1,0,0,0]
            float4 e; e.x = 1.f; e.y = 0.f; e.z = 0.f; e.w = 0.f;
            *(float4*)&At[at_off(k, 32)] = e;
        }
    }
    // ---- stage M_0 into Mbuf[0] ----
    #pragma unroll
    for (int q = 0; q < 2; ++q)
        *(float4*)&Mbuf[q * 2048 + tid * 4] = *(const float4*)&sb[q * 2048 + tid * 4];
    __syncthreads();

    // phase-1 tile coords: 144 workers, 4x4 tiles over 36(rows)x64(cols)
    const bool act1 = tid < 144;
    const int r0 = (tid >> 4) * 4;      // 0,4,...,32
    const int j0 = (tid & 15) * 4;

    float4 creg[4];                     // phase-2 first-chunk prefetch (per wave)

    for (int p = 0; p < 9; ++p) {
        const int mcur = (p & 1) * 4096;
        const int acur = (p & 1) * 2560;
        const int anxt = ((p + 1) & 1) * 2560;

        float4 mst[2];
        if (p < 8) {                    // global->reg prefetch of M_{p+1}
            #pragma unroll
            for (int q = 0; q < 2; ++q)
                mst[q] = *(const float4*)&sb[(p + 1) * 4096 + q * 2048 + tid * 4];
        } else {                        // prefetch phase-2 chunk 0 (t = wave)
            const float* src = sb + (9 + wave) * 4096;
            #pragma unroll
            for (int q = 0; q < 4; ++q)
                creg[q] = *(const float4*)&src[q * 256 + lane * 4];
        }

        float f[4][4];                  // F_{p+1} tile (row-32 tile: [1;0;0;0])
        if (act1) {
            if (r0 < 32) {
                #pragma unroll
                for (int i = 0; i < 4; ++i) {
                    float4 v = *(const float4*)&fb[(p + 1) * 2048 + (r0 + i) * 64 + j0];
                    f[i][0] = v.x; f[i][1] = v.y; f[i][2] = v.z; f[i][3] = v.w;
                }
            } else {
                #pragma unroll
                for (int i = 0; i < 4; ++i)
                    #pragma unroll
                    for (int c = 0; c < 4; ++c) f[i][c] = (i == 0) ? 1.f : 0.f;
            }
        }

        if (act1) {
            float acc[16];
            #pragma unroll
            for (int i = 0; i < 16; ++i) acc[i] = 0.f;
            #pragma unroll 16
            for (int k = 0; k < 64; ++k) {
                const float4 a = *(const float4*)&At[acur + at_off(k, r0)];   // A[r0:+4][k]
                const float4 m = *(const float4*)&Mbuf[mcur + k * 64 + j0];   // M[k][j0:+4]
                acc[0]  += a.x*m.x; acc[1]  += a.x*m.y; acc[2]  += a.x*m.z; acc[3]  += a.x*m.w;
                acc[4]  += a.y*m.x; acc[5]  += a.y*m.y; acc[6]  += a.y*m.z; acc[7]  += a.y*m.w;
                acc[8]  += a.z*m.x; acc[9]  += a.z*m.y; acc[10] += a.z*m.z; acc[11] += a.z*m.w;
                acc[12] += a.w*m.x; acc[13] += a.w*m.y; acc[14] += a.w*m.z; acc[15] += a.w*m.w;
            }
            // epilogue: A' = acc + F', written transposed into At[anxt]
            #pragma unroll
            for (int c = 0; c < 4; ++c) {
                float4 w4;
                w4.x = acc[0*4 + c] + f[0][c];
                w4.y = acc[1*4 + c] + f[1][c];
                w4.z = acc[2*4 + c] + f[2][c];
                w4.w = acc[3*4 + c] + f[3][c];
                *(float4*)&At[anxt + at_off(j0 + c, r0)] = w4;
            }
            if (p == 8 && r0 == 32) {   // contiguous weight row W = A9[32][:]
                float4 w;
                w.x = acc[0] + 1.f; w.y = acc[1] + 1.f;
                w.z = acc[2] + 1.f; w.w = acc[3] + 1.f;
                *(float4*)&Wrow[j0] = w;
            }
        }
        if (p < 8) {                    // spill M_{p+1} into the other buffer
            const int nb = ((p + 1) & 1) * 4096;
            #pragma unroll
            for (int q = 0; q < 2; ++q)
                *(float4*)&Mbuf[nb + q * 2048 + tid * 4] = mst[q];
        }
        __syncthreads();
    }
    // At[2560..] holds [G;W]^T. Phase 2: 8 independent waves, no barriers.
    // wave w handles t = w (and t = w+8 for w<2).
    const int r0b = (lane >> 4) * 8;    // 0,8,16,24
    const int j0b = (lane & 15) * 4;
    float* mch = &Mbuf[wave * 1024];    // this wave's 4KB k-chunk buffer
    const int nt = (wave < 2) ? 2 : 1;

    for (int rd = 0; rd < nt; ++rd) {
        const int t = wave + rd * 8;
        float acc[32];
        #pragma unroll
        for (int i = 0; i < 32; ++i) acc[i] = 0.f;
        float wv = 0.f;

        for (int c = 0; c < 4; ++c) {
            // spill prefetched chunk c (same-wave in-order DS: prior reads done)
            #pragma unroll
            for (int q = 0; q < 4; ++q)
                *(float4*)&mch[q * 256 + lane * 4] = creg[q];
            // prefetch next chunk (same t, or chunk 0 of next t)
            const float* nsrc = nullptr;
            if (c < 3)            nsrc = sb + (9 + t) * 4096 + (c + 1) * 1024;
            else if (rd + 1 < nt) nsrc = sb + (9 + t + 8) * 4096;
            if (nsrc) {
                #pragma unroll
                for (int q = 0; q < 4; ++q)
                    creg[q] = *(const float4*)&nsrc[q * 256 + lane * 4];
            }
            #pragma unroll
            for (int kk = 0; kk < 16; ++kk) {
                const float4 a0 = *(const float4*)&At[2560 + at_off(c * 16 + kk, r0b)];
                const float4 a1 = *(const float4*)&At[2560 + at_off(c * 16 + kk, r0b + 4)];
                const float4 m  = *(const float4*)&mch[kk * 64 + j0b];
                wv += Wrow[c * 16 + kk] * mch[kk * 64 + lane];   // broadcast + stride-1
                acc[0]  += a0.x*m.x; acc[1]  += a0.x*m.y; acc[2]  += a0.x*m.z; acc[3]  += a0.x*m.w;
                acc[4]  += a0.y*m.x; acc[5]  += a0.y*m.y; acc[6]  += a0.y*m.z; acc[7]  += a0.y*m.w;
                acc[8]  += a0.z*m.x; acc[9]  += a0.z*m.y; acc[10] += a0.z*m.z; acc[11] += a0.z*m.w;
                acc[12] += a0.w*m.x; acc[13] += a0.w*m.y; acc[14] += a0.w*m.z; acc[15] += a0.w*m.w;
                acc[16] += a1.x*m.x; acc[17] += a1.x*m.y; acc[18] += a1.x*m.z; acc[19] += a1.x*m.w;
                acc[20] += a1.y*m.x; acc[21] += a1.y*m.y; acc[22] += a1.y*m.z; acc[23] += a1.y*m.w;
                acc[24] += a1.z*m.x; acc[25] += a1.z*m.y; acc[26] += a1.z*m.z; acc[27] += a1.z*m.w;
                acc[28] += a1.w*m.x; acc[29] += a1.w*m.y; acc[30] += a1.w*m.z; acc[31] += a1.w*m.w;
            }
        }
        // redistribute denominator within the wave (in-order DS, no barrier)
        wvec[wave * 64 + lane] = wv;
        float4 wv4 = *(const float4*)&wvec[wave * 64 + j0b];
        float4 rw;
        rw.x = 1.f / (wv4.x + EPSV);
        rw.y = 1.f / (wv4.y + EPSV);
        rw.z = 1.f / (wv4.z + EPSV);
        rw.w = 1.f / (wv4.w + EPSV);

        float* ob = out + ((size_t)b * 10 + t) * 2048;
        #pragma unroll
        for (int i = 0; i < 8; ++i) {
            const int base = (i < 4) ? (i * 4) : (16 + (i - 4) * 4);
            float4 o;
            o.x = acc[base + 0] * rw.x;
            o.y = acc[base + 1] * rw.y;
            o.z = acc[base + 2] * rw.z;
            o.w = acc[base + 3] * rw.w;
            *(float4*)&ob[(r0b + i) * 64 + j0b] = o;
        }
    }
}

extern "C" void kernel_launch(void* const* d_in, const int* in_sizes, int n_in,
                              void* d_out, int out_size, void* d_ws, size_t ws_size,
                              hipStream_t stream) {
    const float* feats = (const float*)d_in[0];
    const float* sim   = (const float*)d_in[1];
    k_fused<<<256, 512, 0, stream>>>(feats, sim, (float*)d_out);
}